// Round 7
// baseline (465.661 us; speedup 1.0000x reference)
//
#include <hip/hip_runtime.h>

#define N_ITEMS 200000
#define EPSV2 1e-16f   // eps on SQUARED norm product: max(sqrt(x),1e-8)=sqrt(max(x,1e-16))
#define INV_TEMP 10.0f

typedef float f32x4 __attribute__((ext_vector_type(4)));

// Inline-asm 16B load: asm volatile CANNOT be sunk/reordered by IR or MIR
// passes (R4/R6 lesson: launch_bounds and sched_barrier both failed to stop
// the compiler clustering plain-C loads into serialized round trips).
// "memory" clobber fences prior stores -> vmcnt FIFO counting stays exact.
#define GLOAD4(dst, ptr) \
    asm volatile("global_load_dwordx4 %0, %1, off" : "=&v"(dst) : "v"(ptr) : "memory")
#define WAITCNT(n) asm volatile("s_waitcnt vmcnt(" #n ")" ::: "memory")

// Stable softplus, matches jax.nn.softplus = logaddexp(x, 0)
__device__ __forceinline__ float softplus_f(float x) {
    return fmaxf(x, 0.0f) + log1pf(expf(-fabsf(x)));
}

__device__ __forceinline__ float dot8(f32x4 a0, f32x4 a1, f32x4 b0, f32x4 b1) {
    f32x4 t = a0 * b0 + a1 * b1;
    return t.x + t.y + t.z + t.w;
}

__global__ void mvr_init_ws(float* ws) {
    if (threadIdx.x < 3) ws[threadIdx.x] = 0.0f;
}

// R7. Geometry = R0 (3125 blocks x 4 waves, 4 sweeps): proven locality
// optimum — compulsory 512 MB traffic in every looped run; every flat
// variant inflated traffic 1.7-2.7x. Limiter: ~25k cycles/wave-iter vs
// ~800 compute because plain-C loads issue in 6-8 serialized clusters.
// R7 forces ONE issue window per iteration via inline-asm loads:
//   issue 8 seq-row loads, then 8 gather loads (asm order = FIFO order)
//   s_waitcnt vmcnt(8)  -> seq rows done, 8 gathers still in flight
//   seq-only dots (~250 VALU ops) overlap the gather round trip
//   s_waitcnt vmcnt(0)  -> gather dots, butterfly, epilogue
// vmcnt is FIFO on CDNA, so the counted waits are exact; "memory" clobbers
// order the previous iteration's 2 stores before the load block.
// All 12 neg-indices preloaded in the prologue (loop fully unrolled ->
// static indexing, no scratch; kills the idx->gather serial chain).
__global__ __launch_bounds__(256, 3) void mvr_main(
    const float* __restrict__ g1, const float* __restrict__ g2,
    const float* __restrict__ s1, const float* __restrict__ s2,
    const float* __restrict__ att_w,
    const int* __restrict__ neg_g, const int* __restrict__ neg_s,
    const int* __restrict__ neg_c,
    float* __restrict__ out, float* __restrict__ loss_acc)
{
    const int tid = threadIdx.x;
    const int lane = tid & 63;
    const int g = lane >> 4;        // item group within wave (0..3)
    const int l = lane & 15;        // lane within group
    const int waveId = blockIdx.x * 4 + (tid >> 6);
    // waveStride = 12500 waves -> item stride per sweep = 50000; 4 sweeps exact.

    const f32x4* G1 = (const f32x4*)g1;
    const f32x4* G2 = (const f32x4*)g2;
    const f32x4* S1 = (const f32x4*)s1;
    const f32x4* S2 = (const f32x4*)s2;
    f32x4* Op = (f32x4*)out;

    // att_w: 256 floats = 64 f32x4. ga-half: idx l, 16+l; sa-half: 32+l, 48+l.
    const f32x4* W = (const f32x4*)att_w;
    const f32x4 wa0 = W[l], wa1 = W[16 + l];
    const f32x4 wb0 = W[32 + l], wb1 = W[48 + l];

    // Prologue: preload ALL neg indices (4 sweeps x 3). Unrolled loop ->
    // compile-time indexing -> registers (rule #20).
    int jgs[4], jss[4], jcs[4];
    #pragma unroll
    for (int s = 0; s < 4; s++) {
        const int it = waveId * 4 + s * 50000 + g;
        jgs[s] = neg_g[it];
        jss[s] = neg_s[it];
        jcs[s] = neg_c[it];
    }

    float accG = 0.0f, accS = 0.0f, accC = 0.0f;

    #pragma unroll
    for (int s = 0; s < 4; s++) {
        const int item = waveId * 4 + s * 50000 + g;
        const size_t rb = (size_t)item * 32;      // row in f32x4 units
        const size_t rg = (size_t)jgs[s] * 32;
        const size_t rs = (size_t)jss[s] * 32;
        const size_t rc = (size_t)jcs[s] * 32;

        f32x4 G1a, G1b, G2a, G2b, S1a, S1b, S2a, S2b;
        f32x4 Gna, Gnb, Sna, Snb, C1a, C1b, C2a, C2b;

        // ---- one issue window: 8 sequential rows first (L2-fast) ----
        GLOAD4(G1a, G1 + rb + l);  GLOAD4(G1b, G1 + rb + 16 + l);
        GLOAD4(G2a, G2 + rb + l);  GLOAD4(G2b, G2 + rb + 16 + l);
        GLOAD4(S1a, S1 + rb + l);  GLOAD4(S1b, S1 + rb + 16 + l);
        GLOAD4(S2a, S2 + rb + l);  GLOAD4(S2b, S2 + rb + 16 + l);
        // ---- then 8 random gathers (long latency, overlapped below) ----
        GLOAD4(Gna, G2 + rg + l);  GLOAD4(Gnb, G2 + rg + 16 + l);
        GLOAD4(Sna, S2 + rs + l);  GLOAD4(Snb, S2 + rs + 16 + l);
        GLOAD4(C1a, S1 + rc + l);  GLOAD4(C1b, S1 + rc + 16 + l);
        GLOAD4(C2a, S2 + rc + l);  GLOAD4(C2b, S2 + rc + 16 + l);

        // Seq rows complete; exactly the 8 gathers remain in flight.
        WAITCNT(8);
        __builtin_amdgcn_sched_barrier(0);

        // ---- sequential-only compute overlaps the gather round trip ----
        f32x4 GAa = (G1a + G2a) * 0.5f, GAb = (G1b + G2b) * 0.5f;
        f32x4 SAa = (S1a + S2a) * 0.5f, SAb = (S1b + S2b) * 0.5f;

        float v[16];
        v[0]  = dot8(G1a, G1b, G2a, G2b);   // g1.g2
        v[1]  = dot8(G1a, G1b, G1a, G1b);   // |g1|^2
        v[2]  = dot8(G2a, G2b, G2a, G2b);   // |g2|^2
        v[5]  = dot8(S1a, S1b, S2a, S2b);
        v[6]  = dot8(S1a, S1b, S1a, S1b);
        v[7]  = dot8(S2a, S2b, S2a, S2b);
        v[10] = dot8(GAa, GAb, SAa, SAb);   // ga.sa
        v[11] = dot8(GAa, GAb, GAa, GAb);   // |ga|^2
        v[12] = dot8(SAa, SAb, SAa, SAb);   // |sa|^2
        v[15] = dot8(GAa, GAb, wa0, wa1) + dot8(SAa, SAb, wb0, wb1); // att dot

        // Gathers complete.
        WAITCNT(0);
        __builtin_amdgcn_sched_barrier(0);

        // ---- gather-dependent compute ----
        f32x4 CNa = (C1a + C2a) * 0.5f, CNb = (C1b + C2b) * 0.5f;
        v[3]  = dot8(G1a, G1b, Gna, Gnb);   // g1.g2[neg]
        v[4]  = dot8(Gna, Gnb, Gna, Gnb);   // |g2[neg]|^2
        v[8]  = dot8(S1a, S1b, Sna, Snb);
        v[9]  = dot8(Sna, Snb, Sna, Snb);
        v[13] = dot8(GAa, GAb, CNa, CNb);   // ga.sa[neg]
        v[14] = dot8(CNa, CNb, CNa, CNb);   // |sa[neg]|^2

        // Butterfly over the 16 lanes of the group; every lane gets the sums.
        #pragma unroll
        for (int off = 8; off > 0; off >>= 1) {
            #pragma unroll
            for (int k = 0; k < 16; k++)
                v[k] += __shfl_xor(v[k], off, 64);
        }

        // cos = num * rsqrt(max(n1sq*n2sq, 1e-16)): same clamp semantics as
        // num / max(sqrt(n1sq*n2sq), 1e-8).
        const float cgp = v[0] * rsqrtf(fmaxf(v[1] * v[2], EPSV2));
        const float cgn = v[3] * rsqrtf(fmaxf(v[1] * v[4], EPSV2));
        accG += softplus_f((cgn - cgp) * INV_TEMP);

        const float csp = v[5] * rsqrtf(fmaxf(v[6] * v[7], EPSV2));
        const float csn = v[8] * rsqrtf(fmaxf(v[6] * v[9], EPSV2));
        accS += softplus_f((csn - csp) * INV_TEMP);

        const float ccp = v[10] * rsqrtf(fmaxf(v[11] * v[12], EPSV2));
        const float ccn = v[13] * rsqrtf(fmaxf(v[11] * v[14], EPSV2));
        accC += softplus_f((ccn - ccp) * INV_TEMP);

        const float alpha = 1.0f / (1.0f + expf(-v[15]));
        f32x4 o0 = SAa + alpha * (GAa - SAa);
        f32x4 o1 = SAb + alpha * (GAb - SAb);
        Op[rb + l] = o0;
        Op[rb + 16 + l] = o1;
    }

    // All 16 lanes of a group hold identical acc values → summing across
    // groups (xor 16, 32) gives each lane the exact sum of the 4 group values.
    accG += __shfl_xor(accG, 16, 64); accG += __shfl_xor(accG, 32, 64);
    accS += __shfl_xor(accS, 16, 64); accS += __shfl_xor(accS, 32, 64);
    accC += __shfl_xor(accC, 16, 64); accC += __shfl_xor(accC, 32, 64);

    __shared__ float sh[4][3];
    const int wave = tid >> 6;
    if (lane == 0) {
        sh[wave][0] = accG;
        sh[wave][1] = accS;
        sh[wave][2] = accC;
    }
    __syncthreads();
    if (tid == 0) {
        float a = 0.0f, b = 0.0f, c = 0.0f;
        #pragma unroll
        for (int w = 0; w < 4; w++) {
            a += sh[w][0]; b += sh[w][1]; c += sh[w][2];
        }
        atomicAdd(&loss_acc[0], a);
        atomicAdd(&loss_acc[1], b);
        atomicAdd(&loss_acc[2], c);
    }
}

__global__ void mvr_finalize(const float* __restrict__ loss_acc,
                             float* __restrict__ out_scalar) {
    if (threadIdx.x == 0) {
        out_scalar[0] = (loss_acc[0] + loss_acc[1] + loss_acc[2]) * (1.0f / (float)N_ITEMS);
    }
}

extern "C" void kernel_launch(void* const* d_in, const int* in_sizes, int n_in,
                              void* d_out, int out_size, void* d_ws, size_t ws_size,
                              hipStream_t stream) {
    const float* g1    = (const float*)d_in[0];
    const float* g2    = (const float*)d_in[1];
    const float* s1    = (const float*)d_in[2];
    const float* s2    = (const float*)d_in[3];
    const float* att_w = (const float*)d_in[4];
    const int*   neg_g = (const int*)d_in[5];
    const int*   neg_s = (const int*)d_in[6];
    const int*   neg_c = (const int*)d_in[7];
    float* out = (float*)d_out;
    float* ws  = (float*)d_ws;   // 3 floats: loss partial sums

    mvr_init_ws<<<1, 64, 0, stream>>>(ws);
    // 3125 blocks × 4 waves × 4 items/wave = 50000 items/sweep → exactly 4 sweeps
    mvr_main<<<3125, 256, 0, stream>>>(g1, g2, s1, s2, att_w,
                                       neg_g, neg_s, neg_c, out, ws);
    mvr_finalize<<<1, 64, 0, stream>>>(ws, out + (size_t)N_ITEMS * 128);
}